// Round 3
// baseline (2003.281 us; speedup 1.0000x reference)
//
#include <hip/hip_runtime.h>
#include <hip/hip_bf16.h>
#include <math.h>

// B=8, T=2048, N_EMBED=1024, G_HEAD=8, V_CLUSTER=512, HEAD_SIZE=128. N=B*T=16384.
#define GHEAD 8
#define VCLUSTER 512
#define HSIZE 128
#define NQ 16384
#define NEMBED 1024

// Kernel 1: per-codeword squared norms -> d_ws (4096 floats).
__global__ __launch_bounds__(256) void pq_norms_kernel(const float* __restrict__ embed,
                                                       float* __restrict__ norms) {
    int v = blockIdx.x * 256 + threadIdx.x;   // 0..4095 (8*512)
    const float4* e = reinterpret_cast<const float4*>(embed + (size_t)v * HSIZE);
    float ax = 0.f, ay = 0.f, az = 0.f, aw = 0.f;
#pragma unroll
    for (int i = 0; i < HSIZE / 4; ++i) {
        float4 ev = e[i];
        ax = fmaf(ev.x, ev.x, ax);
        ay = fmaf(ev.y, ev.y, ay);
        az = fmaf(ev.z, ev.z, az);
        aw = fmaf(ev.w, ev.w, aw);
    }
    norms[v] = (ax + ay) + (az + aw);
}

// Kernel 2: K-split-2 — a lane PAIR owns one (query, group). Each lane holds 64
// of the 128 query floats in VGPRs (pinned); per-codeword half-dots combine via
// DPP quad_perm swap (VALU-speed). 4096 waves = 4 waves/SIMD.
__global__ __launch_bounds__(256, 4) void pq_main_kernel(const float* __restrict__ x,
                                                         const float* __restrict__ embed,
                                                         const float* __restrict__ norms,
                                                         float* __restrict__ out_q,
                                                         float* __restrict__ out_c) {
    const int lane = (int)(threadIdx.x & 63);
    int w = (int)((blockIdx.x << 2) | (threadIdx.x >> 6));   // global wave id 0..4095
    w = __builtin_amdgcn_readfirstlane(w);                   // SGPR-uniform
    const int g     = w >> 9;                 // 512 waves per group
    const int qbase = (w & 511) << 5;         // 32 queries per wave
    const int q     = qbase + (lane >> 1);    // 0..16383
    const int half  = lane & 1;               // which 64-float half of the query

    // Load this lane's half-query: 64 contiguous floats = 16x float4.
    const float4* xp = reinterpret_cast<const float4*>(
        x + (size_t)q * NEMBED + g * HSIZE + half * 64);
    float4 xr[16];
#pragma unroll
    for (int i = 0; i < 16; ++i) xr[i] = xp[i];
    // Pin: force the query to stay materialized in VGPRs (round-2 lesson:
    // compiler rematerialized the query loads inside the codeword loop).
#pragma unroll
    for (int i = 0; i < 16; ++i)
        asm volatile("" : "+v"(xr[i].x), "+v"(xr[i].y), "+v"(xr[i].z), "+v"(xr[i].w));

    // ||x||^2 (half-norm, then pair-combine; commutative add -> bitwise identical on both lanes)
    float ax = 0.f, ay = 0.f, az = 0.f, aw = 0.f;
#pragma unroll
    for (int i = 0; i < 16; ++i) {
        ax = fmaf(xr[i].x, xr[i].x, ax);
        ay = fmaf(xr[i].y, xr[i].y, ay);
        az = fmaf(xr[i].z, xr[i].z, az);
        aw = fmaf(xr[i].w, xr[i].w, aw);
    }
    float halfn = (ax + ay) + (az + aw);
    const float xn2 = halfn + __shfl_xor(halfn, 1);

    const float* eg = embed + (size_t)g * VCLUSTER * HSIZE;  // uniform
    const float* ng = norms + g * VCLUSTER;                  // uniform
    const float* ep = eg + half * 64;                        // per-lane half base

    float m1 = INFINITY, m2 = INFINITY;
    int   i1 = 0, i2 = 0;
#pragma unroll 2
    for (int v = 0; v < VCLUSTER; ++v) {
        const float4* ev = reinterpret_cast<const float4*>(ep + (size_t)v * HSIZE);
        float cx = 0.f, cy = 0.f, cz = 0.f, cw = 0.f;
#pragma unroll
        for (int i = 0; i < 16; ++i) {
            float4 e4 = ev[i];
            cx = fmaf(xr[i].x, e4.x, cx);
            cy = fmaf(xr[i].y, e4.y, cy);
            cz = fmaf(xr[i].z, e4.z, cz);
            cw = fmaf(xr[i].w, e4.w, cw);
        }
        float hd = (cx + cy) + (cz + cw);
        // pair-combine: DPP quad_perm [1,0,3,2] swaps lanes (2i,2i+1) — pure VALU
        float od = __int_as_float(
            __builtin_amdgcn_mov_dpp(__float_as_int(hd), 0xB1, 0xF, 0xF, true));
        float dot = hd + od;
        float d2 = fmaf(-2.0f, dot, xn2 + ng[v]);
        bool b1 = d2 < m1;                 // strict '<' = numpy first-index tie-break
        bool b2 = d2 < m2;
        m2 = b1 ? m1 : (b2 ? d2 : m2);
        i2 = b1 ? i1 : (b2 ? v  : i2);
        m1 = b1 ? d2 : m1;
        i1 = b1 ? v  : i1;
    }

    // fp64 exact re-rank of the top-2 (always; ~1.5% cost, removes fp32 flip risk)
    const float4* e1p = reinterpret_cast<const float4*>(ep + (size_t)i1 * HSIZE);
    const float4* e2p = reinterpret_cast<const float4*>(ep + (size_t)i2 * HSIZE);
    double s1a = 0.0, s1b = 0.0, s2a = 0.0, s2b = 0.0;
#pragma unroll 4
    for (int i = 0; i < 16; ++i) {
        float4 e4 = e1p[i];
        double dx = (double)xr[i].x - (double)e4.x;
        double dy = (double)xr[i].y - (double)e4.y;
        double dz = (double)xr[i].z - (double)e4.z;
        double dw = (double)xr[i].w - (double)e4.w;
        s1a = fma(dx, dx, s1a); s1b = fma(dy, dy, s1b);
        s1a = fma(dz, dz, s1a); s1b = fma(dw, dw, s1b);
    }
#pragma unroll 4
    for (int i = 0; i < 16; ++i) {
        float4 e4 = e2p[i];
        double dx = (double)xr[i].x - (double)e4.x;
        double dy = (double)xr[i].y - (double)e4.y;
        double dz = (double)xr[i].z - (double)e4.z;
        double dw = (double)xr[i].w - (double)e4.w;
        s2a = fma(dx, dx, s2a); s2b = fma(dy, dy, s2b);
        s2a = fma(dz, dz, s2a); s2b = fma(dw, dw, s2b);
    }
    double d1f = s1a + s1b;  d1f += __shfl_xor(d1f, 1);   // commutative: identical on pair
    double d2f = s2a + s2b;  d2f += __shfl_xor(d2f, 1);
    bool pick2 = (d2f < d1f) || (d2f == d1f && i2 < i1);  // tie -> smaller index
    const int best = pick2 ? i2 : i1;

    // quantize output: each lane writes its 64-float half of the winning codeword
    const float4* eb = reinterpret_cast<const float4*>(ep + (size_t)best * HSIZE);
    float4* qo = reinterpret_cast<float4*>(
        out_q + (size_t)q * NEMBED + g * HSIZE + half * 64);
#pragma unroll
    for (int i = 0; i < 16; ++i) qo[i] = eb[i];

    if (half == 0) out_c[(size_t)q * GHEAD + g] = (float)best;
}

extern "C" void kernel_launch(void* const* d_in, const int* in_sizes, int n_in,
                              void* d_out, int out_size, void* d_ws, size_t ws_size,
                              hipStream_t stream) {
    const float* x     = (const float*)d_in[0];   // (8, 2048, 1024) f32
    const float* embed = (const float*)d_in[1];   // (8, 512, 128)  f32
    float* out_q = (float*)d_out;                 // quantize: 16,777,216 f32
    float* out_c = out_q + (size_t)NQ * NEMBED;   // codes (stored as f32)
    float* norms = (float*)d_ws;                  // 4096 f32 scratch

    pq_norms_kernel<<<16, 256, 0, stream>>>(embed, norms);
    pq_main_kernel<<<1024, 256, 0, stream>>>(x, embed, norms, out_q, out_c);
}

// Round 4
// 1979.136 us; speedup vs baseline: 1.0122x; 1.0122x over previous
//
#include <hip/hip_runtime.h>
#include <hip/hip_bf16.h>
#include <math.h>

// B=8, T=2048, N_EMBED=1024, G_HEAD=8, V_CLUSTER=512, HEAD_SIZE=128. N=B*T=16384.
#define GHEAD 8
#define VCLUSTER 512
#define HSIZE 128
#define NQ 16384
#define NEMBED 1024

// Kernel 1: per-codeword squared norms -> d_ws (4096 floats).
__global__ __launch_bounds__(256) void pq_norms_kernel(const float* __restrict__ embed,
                                                       float* __restrict__ norms) {
    int v = blockIdx.x * 256 + threadIdx.x;   // 0..4095 (8*512)
    const float4* e = reinterpret_cast<const float4*>(embed + (size_t)v * HSIZE);
    float ax = 0.f, ay = 0.f, az = 0.f, aw = 0.f;
#pragma unroll
    for (int i = 0; i < HSIZE / 4; ++i) {
        float4 ev = e[i];
        ax = fmaf(ev.x, ev.x, ax);
        ay = fmaf(ev.y, ev.y, ay);
        az = fmaf(ev.z, ev.z, az);
        aw = fmaf(ev.w, ev.w, aw);
    }
    norms[v] = (ax + ay) + (az + aw);
}

// Kernel 2: K-split-2 — a lane PAIR owns one (query, group). Each lane holds 64
// of the 128 query floats in VGPRs; per-codeword half-dots combine via DPP
// quad_perm swap. 4096 waves = 4 waves/SIMD at <=128 VGPR.
// amdgpu_waves_per_eu(4,4): R3 lesson — launch_bounds min-only let the
// occupancy heuristic target 8 waves/EU (64 VGPR) and spill xr to scratch
// (WRITE_SIZE +110MB). Pinning max=4 gives a 128-VGPR budget -> no spill.
__global__ __launch_bounds__(256)
__attribute__((amdgpu_waves_per_eu(4, 4)))
void pq_main_kernel(const float* __restrict__ x,
                    const float* __restrict__ embed,
                    const float* __restrict__ norms,
                    float* __restrict__ out_q,
                    float* __restrict__ out_c) {
    const int lane = (int)(threadIdx.x & 63);
    int w = (int)((blockIdx.x << 2) | (threadIdx.x >> 6));   // global wave id 0..4095
    w = __builtin_amdgcn_readfirstlane(w);                   // SGPR-uniform
    const int g     = w >> 9;                 // 512 waves per group
    const int qbase = (w & 511) << 5;         // 32 queries per wave
    const int q     = qbase + (lane >> 1);    // 0..16383
    const int half  = lane & 1;               // which 64-float half of the query

    // This lane's half-query: 64 contiguous floats = 16x float4 in VGPRs.
    const float4* xp = reinterpret_cast<const float4*>(
        x + (size_t)q * NEMBED + g * HSIZE + half * 64);
    float4 xr[16];
#pragma unroll
    for (int i = 0; i < 16; ++i) xr[i] = xp[i];

    // ||x||^2 half-norm, pair-combined (commutative add -> bitwise equal on pair)
    float ax = 0.f, ay = 0.f, az = 0.f, aw = 0.f;
#pragma unroll
    for (int i = 0; i < 16; ++i) {
        ax = fmaf(xr[i].x, xr[i].x, ax);
        ay = fmaf(xr[i].y, xr[i].y, ay);
        az = fmaf(xr[i].z, xr[i].z, az);
        aw = fmaf(xr[i].w, xr[i].w, aw);
    }
    float halfn = (ax + ay) + (az + aw);
    const float xn2 = halfn + __shfl_xor(halfn, 1);

    const float* eg = embed + (size_t)g * VCLUSTER * HSIZE;  // uniform
    const float* ng = norms + g * VCLUSTER;                  // uniform
    const float* ep = eg + half * 64;                        // 2 addrs per wave

    float m1 = INFINITY, m2 = INFINITY;
    int   i1 = 0, i2 = 0;
#pragma unroll 2
    for (int v = 0; v < VCLUSTER; ++v) {
        const float4* ev = reinterpret_cast<const float4*>(ep + (size_t)v * HSIZE);
        float cx = 0.f, cy = 0.f, cz = 0.f, cw = 0.f;
#pragma unroll
        for (int i = 0; i < 16; ++i) {
            float4 e4 = ev[i];
            cx = fmaf(xr[i].x, e4.x, cx);
            cy = fmaf(xr[i].y, e4.y, cy);
            cz = fmaf(xr[i].z, e4.z, cz);
            cw = fmaf(xr[i].w, e4.w, cw);
        }
        float hd = (cx + cy) + (cz + cw);
        // pair-combine: DPP quad_perm [1,0,3,2] swaps lanes (2i,2i+1)
        float od = __int_as_float(
            __builtin_amdgcn_mov_dpp(__float_as_int(hd), 0xB1, 0xF, 0xF, true));
        float dot = hd + od;
        float d2 = fmaf(-2.0f, dot, xn2 + ng[v]);
        bool b1 = d2 < m1;                 // strict '<' = numpy first-index tie-break
        bool b2 = d2 < m2;
        m2 = b1 ? m1 : (b2 ? d2 : m2);
        i2 = b1 ? i1 : (b2 ? v  : i2);
        m1 = b1 ? d2 : m1;
        i1 = b1 ? v  : i1;
    }

    // fp64 exact re-rank of the top-2 (removes fp32 ranking-flip risk; ~1.5%)
    const float4* e1p = reinterpret_cast<const float4*>(ep + (size_t)i1 * HSIZE);
    const float4* e2p = reinterpret_cast<const float4*>(ep + (size_t)i2 * HSIZE);
    double s1a = 0.0, s1b = 0.0, s2a = 0.0, s2b = 0.0;
#pragma unroll 4
    for (int i = 0; i < 16; ++i) {
        float4 e4 = e1p[i];
        double dx = (double)xr[i].x - (double)e4.x;
        double dy = (double)xr[i].y - (double)e4.y;
        double dz = (double)xr[i].z - (double)e4.z;
        double dw = (double)xr[i].w - (double)e4.w;
        s1a = fma(dx, dx, s1a); s1b = fma(dy, dy, s1b);
        s1a = fma(dz, dz, s1a); s1b = fma(dw, dw, s1b);
    }
#pragma unroll 4
    for (int i = 0; i < 16; ++i) {
        float4 e4 = e2p[i];
        double dx = (double)xr[i].x - (double)e4.x;
        double dy = (double)xr[i].y - (double)e4.y;
        double dz = (double)xr[i].z - (double)e4.z;
        double dw = (double)xr[i].w - (double)e4.w;
        s2a = fma(dx, dx, s2a); s2b = fma(dy, dy, s2b);
        s2a = fma(dz, dz, s2a); s2b = fma(dw, dw, s2b);
    }
    double d1f = s1a + s1b;  d1f += __shfl_xor(d1f, 1);   // commutative: equal on pair
    double d2f = s2a + s2b;  d2f += __shfl_xor(d2f, 1);
    bool pick2 = (d2f < d1f) || (d2f == d1f && i2 < i1);  // tie -> smaller index
    const int best = pick2 ? i2 : i1;

    // quantize output: each lane writes its 64-float half of the winning codeword
    const float4* eb = reinterpret_cast<const float4*>(ep + (size_t)best * HSIZE);
    float4* qo = reinterpret_cast<float4*>(
        out_q + (size_t)q * NEMBED + g * HSIZE + half * 64);
#pragma unroll
    for (int i = 0; i < 16; ++i) qo[i] = eb[i];

    if (half == 0) out_c[(size_t)q * GHEAD + g] = (float)best;
}

extern "C" void kernel_launch(void* const* d_in, const int* in_sizes, int n_in,
                              void* d_out, int out_size, void* d_ws, size_t ws_size,
                              hipStream_t stream) {
    const float* x     = (const float*)d_in[0];   // (8, 2048, 1024) f32
    const float* embed = (const float*)d_in[1];   // (8, 512, 128)  f32
    float* out_q = (float*)d_out;                 // quantize: 16,777,216 f32
    float* out_c = out_q + (size_t)NQ * NEMBED;   // codes (stored as f32)
    float* norms = (float*)d_ws;                  // 4096 f32 scratch

    pq_norms_kernel<<<16, 256, 0, stream>>>(embed, norms);
    pq_main_kernel<<<1024, 256, 0, stream>>>(x, embed, norms, out_q, out_c);
}

// Round 5
// 322.164 us; speedup vs baseline: 6.2182x; 6.1433x over previous
//
#include <hip/hip_runtime.h>
#include <hip/hip_bf16.h>
#include <math.h>

// B=8, T=2048, N_EMBED=1024, G_HEAD=8, V_CLUSTER=512, HEAD_SIZE=128. N=B*T=16384.
#define GHEAD 8
#define VCLUSTER 512
#define HSIZE 128
#define NQ 16384
#define NEMBED 1024

typedef __attribute__((ext_vector_type(8))) short bf16x8;
typedef __attribute__((ext_vector_type(4))) float f32x4;

// ---------------- Prologue 1: f32 codebook -> bf16 hi/lo split ----------------
__global__ __launch_bounds__(256) void pq_prep_kernel(const float* __restrict__ embed,
                                                      ushort* __restrict__ bhi,
                                                      ushort* __restrict__ blo) {
    int i = blockIdx.x * 256 + threadIdx.x;         // 0..524287 (8*512*128)
    float v = embed[i];
    unsigned u  = __float_as_uint(v);
    unsigned hr = (u + 0x7fffu + ((u >> 16) & 1u)) >> 16;   // RNE to bf16
    float hf = __uint_as_float(hr << 16);
    float lv = v - hf;                                       // exact
    unsigned ul = __float_as_uint(lv);
    unsigned lr = (ul + 0x7fffu + ((ul >> 16) & 1u)) >> 16;
    bhi[i] = (ushort)hr;
    blo[i] = (ushort)lr;
}

// ---------------- Prologue 2: per-codeword squared norms (f32) ----------------
__global__ __launch_bounds__(256) void pq_norms_kernel(const float* __restrict__ embed,
                                                       float* __restrict__ norms) {
    int v = blockIdx.x * 256 + threadIdx.x;   // 0..4095
    const float4* e = reinterpret_cast<const float4*>(embed + (size_t)v * HSIZE);
    float ax = 0.f, ay = 0.f, az = 0.f, aw = 0.f;
#pragma unroll
    for (int i = 0; i < HSIZE / 4; ++i) {
        float4 ev = e[i];
        ax = fmaf(ev.x, ev.x, ax);
        ay = fmaf(ev.y, ev.y, ay);
        az = fmaf(ev.z, ev.z, az);
        aw = fmaf(ev.w, ev.w, aw);
    }
    norms[v] = (ax + ay) + (az + aw);
}

#define MFMA16(A, B, C) __builtin_amdgcn_mfma_f32_16x16x32_bf16((A), (B), (C), 0, 0, 0)

// ---------------- Main: MFMA distance GEMM + fused argmin ----------------
// One wave: 32 queries (2 row-reps of 16) x all 512 codewords of its group.
// Rank by s = ||e||^2 - 2*x.e  (||x||^2 irrelevant to argmin).
// x.e via bf16 split: hi*hi + hi*lo + lo*hi  (error ~1e-5, fp64 rerank safety net).
__global__ __launch_bounds__(256) void pq_mfma_kernel(const float* __restrict__ x,
                                                      const float* __restrict__ embed,
                                                      const ushort* __restrict__ bhi,
                                                      const ushort* __restrict__ blo,
                                                      const float* __restrict__ ng,
                                                      float* __restrict__ out_q,
                                                      float* __restrict__ out_c) {
    __shared__ int sI1[4][32], sI2[4][32];
    const int tid  = (int)threadIdx.x;
    const int lane = tid & 63;
    const int wid  = tid >> 6;
    int w = __builtin_amdgcn_readfirstlane((int)(blockIdx.x * 4 + wid)); // 0..4095
    const int g     = w >> 9;              // 512 waves per group
    const int qbase = (w & 511) << 5;      // 32 queries per wave
    const int lo4   = lane & 15;
    const int hi2   = lane >> 4;

    // ---- A fragments: 2 reps x 4 k-chunks, hi/lo bf16, converted in-register ----
    // A-frag (16x16x32): lane holds row=lane&15, k = c*32 + (lane>>4)*8 + i.
    bf16x8 ahi[2][4], alo[2][4];
#pragma unroll
    for (int r = 0; r < 2; ++r) {
        const float* xq = x + (size_t)(qbase + r * 16 + lo4) * NEMBED + g * HSIZE + hi2 * 8;
#pragma unroll
        for (int c = 0; c < 4; ++c) {
            const float4* xp = reinterpret_cast<const float4*>(xq + c * 32);
            float4 f0 = xp[0], f1 = xp[1];
            float vals[8] = {f0.x, f0.y, f0.z, f0.w, f1.x, f1.y, f1.z, f1.w};
            bf16x8 h, l;
#pragma unroll
            for (int i = 0; i < 8; ++i) {
                float v = vals[i];
                unsigned u  = __float_as_uint(v);
                unsigned hr = (u + 0x7fffu + ((u >> 16) & 1u)) >> 16;
                float hf = __uint_as_float(hr << 16);
                float lv = v - hf;
                unsigned ul = __float_as_uint(lv);
                unsigned lr = (ul + 0x7fffu + ((ul >> 16) & 1u)) >> 16;
                h[i] = (short)hr;
                l[i] = (short)lr;
            }
            ahi[r][c] = h;
            alo[r][c] = l;
        }
    }

    const ushort* bhg = bhi + (size_t)g * VCLUSTER * HSIZE + hi2 * 8;
    const ushort* blg = blo + (size_t)g * VCLUSTER * HSIZE + hi2 * 8;
    const float*  ngg = ng + g * VCLUSTER;

    float m1[8], m2[8];
    int   i1[8], i2a[8];
#pragma unroll
    for (int k = 0; k < 8; ++k) { m1[k] = INFINITY; m2[k] = INFINITY; i1[k] = 0; i2a[k] = 0; }

    // ---- tile loop: 32 tiles of 16 codewords ----
    for (int t = 0; t < 32; ++t) {
        const ushort* bp = bhg + (size_t)(t * 16 + lo4) * HSIZE;  // B-frag: col=lane&15
        const ushort* bq = blg + (size_t)(t * 16 + lo4) * HSIZE;
        f32x4 acc0 = {0.f, 0.f, 0.f, 0.f};
        f32x4 acc1 = {0.f, 0.f, 0.f, 0.f};
        bf16x8 bh0 = *reinterpret_cast<const bf16x8*>(bp);
        bf16x8 bh1 = *reinterpret_cast<const bf16x8*>(bp + 32);
        bf16x8 bh2 = *reinterpret_cast<const bf16x8*>(bp + 64);
        bf16x8 bh3 = *reinterpret_cast<const bf16x8*>(bp + 96);
        // hi*hi
        acc0 = MFMA16(ahi[0][0], bh0, acc0);  acc1 = MFMA16(ahi[1][0], bh0, acc1);
        acc0 = MFMA16(ahi[0][1], bh1, acc0);  acc1 = MFMA16(ahi[1][1], bh1, acc1);
        acc0 = MFMA16(ahi[0][2], bh2, acc0);  acc1 = MFMA16(ahi[1][2], bh2, acc1);
        acc0 = MFMA16(ahi[0][3], bh3, acc0);  acc1 = MFMA16(ahi[1][3], bh3, acc1);
        // hi*lo + lo*hi
        {
            bf16x8 bl0 = *reinterpret_cast<const bf16x8*>(bq);
            acc0 = MFMA16(ahi[0][0], bl0, acc0);  acc1 = MFMA16(ahi[1][0], bl0, acc1);
            acc0 = MFMA16(alo[0][0], bh0, acc0);  acc1 = MFMA16(alo[1][0], bh0, acc1);
            bf16x8 bl1 = *reinterpret_cast<const bf16x8*>(bq + 32);
            acc0 = MFMA16(ahi[0][1], bl1, acc0);  acc1 = MFMA16(ahi[1][1], bl1, acc1);
            acc0 = MFMA16(alo[0][1], bh1, acc0);  acc1 = MFMA16(alo[1][1], bh1, acc1);
            bf16x8 bl2 = *reinterpret_cast<const bf16x8*>(bq + 64);
            acc0 = MFMA16(ahi[0][2], bl2, acc0);  acc1 = MFMA16(ahi[1][2], bl2, acc1);
            acc0 = MFMA16(alo[0][2], bh2, acc0);  acc1 = MFMA16(alo[1][2], bh2, acc1);
            bf16x8 bl3 = *reinterpret_cast<const bf16x8*>(bq + 96);
            acc0 = MFMA16(ahi[0][3], bl3, acc0);  acc1 = MFMA16(ahi[1][3], bl3, acc1);
            acc0 = MFMA16(alo[0][3], bh3, acc0);  acc1 = MFMA16(alo[1][3], bh3, acc1);
        }
        // epilogue: s = ng[v] - 2*dot ; top-2 per (rep, reg-row)
        const float ngv = ngg[t * 16 + lo4];
        const int   v   = t * 16 + lo4;
#pragma unroll
        for (int r = 0; r < 2; ++r) {
#pragma unroll
            for (int j = 0; j < 4; ++j) {
                float d = (r == 0) ? acc0[j] : acc1[j];
                float s = fmaf(-2.0f, d, ngv);
                int k = r * 4 + j;
                bool b1 = s < m1[k];           // strict: first-index tie-break
                bool b2 = s < m2[k];
                m2[k]  = b1 ? m1[k] : (b2 ? s : m2[k]);
                i2a[k] = b1 ? i1[k] : (b2 ? v : i2a[k]);
                m1[k]  = b1 ? s : m1[k];
                i1[k]  = b1 ? v : i1[k];
            }
        }
    }

    // ---- merge top-2 across the 16 lanes sharing the same C-rows (low 4 lane bits) ----
#pragma unroll
    for (int msk = 1; msk <= 8; msk <<= 1) {
#pragma unroll
        for (int k = 0; k < 8; ++k) {
            float pm1 = __shfl_xor(m1[k], msk);   int pi1 = __shfl_xor(i1[k], msk);
            float pm2 = __shfl_xor(m2[k], msk);   int pi2 = __shfl_xor(i2a[k], msk);
            bool b = pm1 < m1[k];
            float w1 = b ? pm1 : m1[k];   int wi1 = b ? pi1 : i1[k];
            float lz = b ? m1[k] : pm1;   int li  = b ? i1[k] : pi1;
            float cs = b ? pm2 : m2[k];   int ci  = b ? pi2 : i2a[k];
            bool c2 = cs < lz;
            m1[k] = w1;  i1[k] = wi1;
            m2[k] = c2 ? cs : lz;  i2a[k] = c2 ? ci : li;
        }
    }

    // ---- redistribute (i1,i2) per query via LDS; epilogue = R2's verified lane-pair rerank ----
    if (lo4 == 0) {
#pragma unroll
        for (int r = 0; r < 2; ++r)
#pragma unroll
            for (int j = 0; j < 4; ++j) {
                int qloc = r * 16 + hi2 * 4 + j;   // C-row mapping: row=(lane>>4)*4+reg
                sI1[wid][qloc] = i1[r * 4 + j];
                sI2[wid][qloc] = i2a[r * 4 + j];
            }
    }
    __syncthreads();

    const int qloc = lane >> 1;
    const int half = lane & 1;
    const int q    = qbase + qloc;
    const int ii1  = sI1[wid][qloc];
    const int ii2  = sI2[wid][qloc];

    // re-read this lane's half-query (L2-warm)
    const float4* xp2 = reinterpret_cast<const float4*>(
        x + (size_t)q * NEMBED + g * HSIZE + half * 64);
    float4 xr[16];
#pragma unroll
    for (int i = 0; i < 16; ++i) xr[i] = xp2[i];

    const float* egf = embed + (size_t)g * VCLUSTER * HSIZE + half * 64;
    const float4* e1p = reinterpret_cast<const float4*>(egf + (size_t)ii1 * HSIZE);
    const float4* e2p = reinterpret_cast<const float4*>(egf + (size_t)ii2 * HSIZE);
    double s1a = 0.0, s1b = 0.0, s2a = 0.0, s2b = 0.0;
#pragma unroll 4
    for (int i = 0; i < 16; ++i) {
        float4 e4 = e1p[i];
        double dx = (double)xr[i].x - (double)e4.x;
        double dy = (double)xr[i].y - (double)e4.y;
        double dz = (double)xr[i].z - (double)e4.z;
        double dw = (double)xr[i].w - (double)e4.w;
        s1a = fma(dx, dx, s1a); s1b = fma(dy, dy, s1b);
        s1a = fma(dz, dz, s1a); s1b = fma(dw, dw, s1b);
    }
#pragma unroll 4
    for (int i = 0; i < 16; ++i) {
        float4 e4 = e2p[i];
        double dx = (double)xr[i].x - (double)e4.x;
        double dy = (double)xr[i].y - (double)e4.y;
        double dz = (double)xr[i].z - (double)e4.z;
        double dw = (double)xr[i].w - (double)e4.w;
        s2a = fma(dx, dx, s2a); s2b = fma(dy, dy, s2b);
        s2a = fma(dz, dz, s2a); s2b = fma(dw, dw, s2b);
    }
    double d1f = s1a + s1b;  d1f += __shfl_xor(d1f, 1);   // commutative: equal on pair
    double d2f = s2a + s2b;  d2f += __shfl_xor(d2f, 1);
    bool pick2 = (d2f < d1f) || (d2f == d1f && ii2 < ii1);
    const int best = pick2 ? ii2 : ii1;

    const float4* eb = reinterpret_cast<const float4*>(egf + (size_t)best * HSIZE);
    float4* qo = reinterpret_cast<float4*>(
        out_q + (size_t)q * NEMBED + g * HSIZE + half * 64);
#pragma unroll
    for (int i = 0; i < 16; ++i) qo[i] = eb[i];

    if (half == 0) out_c[(size_t)q * GHEAD + g] = (float)best;
}

// ---------------- Fallback (ws too small): R2's verified fp32 kernel ----------------
__global__ __launch_bounds__(256, 2) void pq_fb_kernel(const float* __restrict__ x,
                                                       const float* __restrict__ embed,
                                                       const float* __restrict__ norms,
                                                       float* __restrict__ out_q,
                                                       float* __restrict__ out_c) {
    int wv = (int)((blockIdx.x * 256u + threadIdx.x) >> 6);
    wv = __builtin_amdgcn_readfirstlane(wv);
    const int lane  = (int)(threadIdx.x & 63);
    const int g     = wv >> 8;
    const int n     = (wv & 255) * 64 + lane;
    const float4* xp = reinterpret_cast<const float4*>(x + (size_t)n * NEMBED + g * HSIZE);
    float4 xr[32];
#pragma unroll
    for (int i = 0; i < 32; ++i) xr[i] = xp[i];
    float ax = 0.f, ay = 0.f, az = 0.f, aw = 0.f;
#pragma unroll
    for (int i = 0; i < 32; ++i) {
        ax = fmaf(xr[i].x, xr[i].x, ax); ay = fmaf(xr[i].y, xr[i].y, ay);
        az = fmaf(xr[i].z, xr[i].z, az); aw = fmaf(xr[i].w, xr[i].w, aw);
    }
    const float xn2 = (ax + ay) + (az + aw);
    const float* eg = embed + (size_t)g * VCLUSTER * HSIZE;
    const float* ngp = norms + g * VCLUSTER;
    float m1 = INFINITY, m2 = INFINITY;  int i1 = 0, i2 = 0;
#pragma unroll 2
    for (int v = 0; v < VCLUSTER; ++v) {
        const float4* ev = reinterpret_cast<const float4*>(eg + (size_t)v * HSIZE);
        float cx = 0.f, cy = 0.f, cz = 0.f, cw = 0.f;
#pragma unroll
        for (int i = 0; i < 32; ++i) {
            float4 e4 = ev[i];
            cx = fmaf(xr[i].x, e4.x, cx); cy = fmaf(xr[i].y, e4.y, cy);
            cz = fmaf(xr[i].z, e4.z, cz); cw = fmaf(xr[i].w, e4.w, cw);
        }
        float d2 = fmaf(-2.0f, (cx + cy) + (cz + cw), xn2 + ngp[v]);
        bool b1 = d2 < m1; bool b2 = d2 < m2;
        m2 = b1 ? m1 : (b2 ? d2 : m2); i2 = b1 ? i1 : (b2 ? v : i2);
        m1 = b1 ? d2 : m1;             i1 = b1 ? v : i1;
    }
    int best_i = i1;
    if (__any((m2 - m1) < 0.25f)) {
        const float4* e1p = reinterpret_cast<const float4*>(eg + (size_t)i1 * HSIZE);
        const float4* e2p = reinterpret_cast<const float4*>(eg + (size_t)i2 * HSIZE);
        double s1a = 0.0, s1b = 0.0, s2a = 0.0, s2b = 0.0;
#pragma unroll 4
        for (int i = 0; i < 32; ++i) {
            float4 e4 = e1p[i];
            double dx = (double)xr[i].x - e4.x, dy = (double)xr[i].y - e4.y;
            double dz = (double)xr[i].z - e4.z, dw = (double)xr[i].w - e4.w;
            s1a = fma(dx, dx, s1a); s1b = fma(dy, dy, s1b);
            s1a = fma(dz, dz, s1a); s1b = fma(dw, dw, s1b);
        }
#pragma unroll 4
        for (int i = 0; i < 32; ++i) {
            float4 e4 = e2p[i];
            double dx = (double)xr[i].x - e4.x, dy = (double)xr[i].y - e4.y;
            double dz = (double)xr[i].z - e4.z, dw = (double)xr[i].w - e4.w;
            s2a = fma(dx, dx, s2a); s2b = fma(dy, dy, s2b);
            s2a = fma(dz, dz, s2a); s2b = fma(dw, dw, s2b);
        }
        double d1 = s1a + s1b, d2v = s2a + s2b;
        bool pick2 = (d2v < d1) || (d2v == d1 && i2 < i1);
        best_i = pick2 ? i2 : i1;
    }
    const float4* eb = reinterpret_cast<const float4*>(eg + (size_t)best_i * HSIZE);
    float4* qo = reinterpret_cast<float4*>(out_q + (size_t)n * NEMBED + g * HSIZE);
#pragma unroll
    for (int i = 0; i < 32; ++i) qo[i] = eb[i];
    out_c[(size_t)n * GHEAD + g] = (float)best_i;
}

extern "C" void kernel_launch(void* const* d_in, const int* in_sizes, int n_in,
                              void* d_out, int out_size, void* d_ws, size_t ws_size,
                              hipStream_t stream) {
    const float* x     = (const float*)d_in[0];   // (8, 2048, 1024) f32
    const float* embed = (const float*)d_in[1];   // (8, 512, 128)  f32
    float* out_q = (float*)d_out;
    float* out_c = out_q + (size_t)NQ * NEMBED;

    const size_t NEEDED = (size_t)2 * 1024 * 1024 + 16 * 1024;
    if (ws_size >= NEEDED) {
        ushort* bhi = (ushort*)d_ws;                              // 1 MB
        ushort* blo = (ushort*)((char*)d_ws + (1u << 20));        // 1 MB
        float*  ng  = (float*)((char*)d_ws + (2u << 20));         // 16 KB
        pq_prep_kernel<<<2048, 256, 0, stream>>>(embed, bhi, blo);
        pq_norms_kernel<<<16, 256, 0, stream>>>(embed, ng);
        pq_mfma_kernel<<<1024, 256, 0, stream>>>(x, embed, bhi, blo, ng, out_q, out_c);
    } else {
        float* ng = (float*)d_ws;
        pq_norms_kernel<<<16, 256, 0, stream>>>(embed, ng);
        pq_fb_kernel<<<512, 256, 0, stream>>>(x, embed, ng, out_q, out_c);
    }
}